// Round 8
// baseline (74.695 us; speedup 1.0000x reference)
//
#include <hip/hip_runtime.h>

#define HW     (768*768)       // 589824 pixels per plane
#define N4     (HW/4)          // 147456 float4 groups per plane
#define N4ALL  (8*N4)          // 1179648 groups over the batch
#define MAXI   33
#define LUTN   (MAXI+1)        // 34 (entry 33 = weight 0)
#define B_IMG  8
#define NTHR   256
// pass1 geometry (unchanged from R7)
#define NBLK1  1536
#define NJ1    3
#define GPB1   (NTHR*NJ1)
#define BPI1   192
// pass2 geometry: 3 channels x 512 blocks, 9 iters each, 3 streams per wave
#define CBLK   512             // blocks per channel
#define NBLK2  (3*CBLK)        // 1536 = 6/CU, single round
#define NJ2    9
#define GPB2   (NTHR*NJ2)      // 2304 groups per block; 2304*64 == N4 (64 blk/img)

// ws: 0 g_counts int[8][33] | 4096 g_lut float[8][34] | 8192 partials float[1536]
//     65536 widx byte plane (4.72 MB)

// ---------- Pass 1: ballot histogram + ci-fused widx byte plane ----------
__global__ __launch_bounds__(NTHR, 6) void pass1_count(
    const int* __restrict__ inst, const int* __restrict__ ign,
    const float* __restrict__ gci,
    int* __restrict__ g_counts, uchar4* __restrict__ wbp, int write_bytes)
{
    const int bid  = blockIdx.x;
    const int b    = bid / BPI1;
    const int lane = threadIdx.x & 63;
    const int wv   = threadIdx.x >> 6;
    const int4*   ip  = (const int4*)inst;
    const int4*   gp  = (const int4*)ign;
    const float4* cip = (const float4*)gci;

    int acc = 0;   // count for bin == lane (lanes 0..32 hold bins)

    #pragma unroll
    for (int j = 0; j < NJ1; ++j) {
        const int g = bid * GPB1 + j * NTHR + threadIdx.x;
        int4   id4 = ip[g];
        int4   g4  = gp[g];
        float4 ci  = cip[g];
        int c0 = (g4.x == 0) ? id4.x : MAXI;
        int c1 = (g4.y == 0) ? id4.y : MAXI;
        int c2 = (g4.z == 0) ? id4.z : MAXI;
        int c3 = (g4.w == 0) ? id4.w : MAXI;
        if (write_bytes) {
            int e0 = (ci.x != 0.f) ? c0 : MAXI;
            int e1 = (ci.y != 0.f) ? c1 : MAXI;
            int e2 = (ci.z != 0.f) ? c2 : MAXI;
            int e3 = (ci.w != 0.f) ? c3 : MAXI;
            wbp[g] = make_uchar4((unsigned char)e0, (unsigned char)e1,
                                 (unsigned char)e2, (unsigned char)e3);
        }
        for (int k = 0; k < MAXI; ++k) {
            int cc = __popcll(__ballot(c0 == k)) + __popcll(__ballot(c1 == k))
                   + __popcll(__ballot(c2 == k)) + __popcll(__ballot(c3 == k));
            acc += (lane == k) ? cc : 0;
        }
    }

    __shared__ int s_cnt[NTHR / 64][MAXI];
    if (lane < MAXI) s_cnt[wv][lane] = acc;
    __syncthreads();
    if (threadIdx.x < MAXI) {
        int t = 0;
        #pragma unroll
        for (int w = 0; w < NTHR / 64; ++w) t += s_cnt[w][threadIdx.x];
        atomicAdd(&g_counts[b * MAXI + threadIdx.x], t);
    }
}

// ---------- LUT build: one wave per image (kernel boundary = coherence) ----------
__global__ __launch_bounds__(64) void build_lut(
    const int* __restrict__ g_counts, float* __restrict__ g_lut)
{
    const int b = blockIdx.x;
    const int k = threadIdx.x;
    int cnt = (k < MAXI) ? g_counts[b * MAXI + k] : 0;
    unsigned long long m = __ballot(k >= 1 && k < MAXI && cnt > 0);
    float n = fmaxf((float)__popcll(m), 1.0f);
    if (k < LUTN) {
        float f = 0.f;
        if (k < MAXI) {
            f = 1.0f / fmaxf((float)cnt, 1.0f);
            if (k > 0) f /= n;
        }
        g_lut[b * LUTN + k] = f;
    }
}

// ---------- Pass 2: channel-split weighted L1 — 3 streams per wave ----------
template<int SRC>   // 1 = byte plane, 0 = fallback raw inst/ign/ci (5 streams)
__global__ __launch_bounds__(NTHR, 6) void pass2_loss(
    const float* __restrict__ pred, const uchar4* __restrict__ wbp,
    const int* __restrict__ inst, const int* __restrict__ ign,
    const float* __restrict__ gci,
    const float* __restrict__ gtR, const float* __restrict__ gts,
    const float* __restrict__ gtc,
    const float* __restrict__ g_lut, float* __restrict__ partials)
{
    const int bid  = blockIdx.x;
    const int c    = bid / CBLK;          // channel 0=sin 1=cos 2=r (uniform)
    const int bid2 = bid - c * CBLK;      // 0..511 within channel
    const int b    = bid2 / 64;           // image (64 blocks per image)

    __shared__ float lut[LUTN];
    if (threadIdx.x < LUTN) lut[threadIdx.x] = g_lut[b * LUTN + threadIdx.x];
    __syncthreads();

    const float* gt_sel = (c == 0) ? gts : (c == 1) ? gtc : gtR;
    const float4* G = (const float4*)gt_sel;                    // batch-global index
    const float4* P = (const float4*)pred + (size_t)(b * 3 + c) * N4;  // image-local
    const int4*   ipp = (const int4*)inst;
    const int4*   gpp = (const int4*)ign;
    const float4* cip = (const float4*)gci;

    const int ag0 = bid2 * GPB2 + threadIdx.x;   // batch-global group base
    const int lg0 = ag0 - b * N4;                // image-local group base
    const bool isR = (c == 2);

    float acc = 0.f;

    // 2-deep software pipeline, fully unrolled (NJ2 = 9 exact)
    float4 p_cur, q_cur;
    int w0c, w1c, w2c, w3c;
    {
        p_cur = P[lg0];
        q_cur = G[ag0];
        if constexpr (SRC) {
            uchar4 u = wbp[ag0];
            w0c = u.x; w1c = u.y; w2c = u.z; w3c = u.w;
        } else {
            int4 id4 = ipp[ag0]; int4 g4 = gpp[ag0]; float4 ci = cip[ag0];
            w0c = (g4.x == 0 && ci.x != 0.f) ? id4.x : MAXI;
            w1c = (g4.y == 0 && ci.y != 0.f) ? id4.y : MAXI;
            w2c = (g4.z == 0 && ci.z != 0.f) ? id4.z : MAXI;
            w3c = (g4.w == 0 && ci.w != 0.f) ? id4.w : MAXI;
        }
    }
    #pragma unroll
    for (int j = 0; j < NJ2; ++j) {
        float4 p_nxt, q_nxt;
        int w0n = 0, w1n = 0, w2n = 0, w3n = 0;
        if (j + 1 < NJ2) {
            const int agn = ag0 + (j + 1) * NTHR;
            const int lgn = lg0 + (j + 1) * NTHR;
            p_nxt = P[lgn];
            q_nxt = G[agn];
            if constexpr (SRC) {
                uchar4 u = wbp[agn];
                w0n = u.x; w1n = u.y; w2n = u.z; w3n = u.w;
            } else {
                int4 id4 = ipp[agn]; int4 g4 = gpp[agn]; float4 ci = cip[agn];
                w0n = (g4.x == 0 && ci.x != 0.f) ? id4.x : MAXI;
                w1n = (g4.y == 0 && ci.y != 0.f) ? id4.y : MAXI;
                w2n = (g4.z == 0 && ci.z != 0.f) ? id4.z : MAXI;
                w3n = (g4.w == 0 && ci.w != 0.f) ? id4.w : MAXI;
            }
        }
        // consume current
        float g0 = q_cur.x, g1 = q_cur.y, g2 = q_cur.z, g3 = q_cur.w;
        if (isR) {
            g0 = __logf(g0 + 1.f); g1 = __logf(g1 + 1.f);
            g2 = __logf(g2 + 1.f); g3 = __logf(g3 + 1.f);
        }
        acc += lut[w0c] * fabsf(p_cur.x - g0)
             + lut[w1c] * fabsf(p_cur.y - g1)
             + lut[w2c] * fabsf(p_cur.z - g2)
             + lut[w3c] * fabsf(p_cur.w - g3);
        p_cur = p_nxt; q_cur = q_nxt;
        w0c = w0n; w1c = w1n; w2c = w2n; w3c = w3n;
    }

    #pragma unroll
    for (int o = 32; o > 0; o >>= 1) acc += __shfl_down(acc, o);
    __shared__ float sred[NTHR / 64];
    const int wv = threadIdx.x >> 6, lane = threadIdx.x & 63;
    if (lane == 0) sred[wv] = acc;
    __syncthreads();
    if (threadIdx.x == 0) {
        float t = 0.f;
        #pragma unroll
        for (int w = 0; w < NTHR / 64; ++w) t += sred[w];
        partials[bid] = t;
    }
}

// ---------- Finalize: 8 blocks; each reduces 3 channels x 64 block-partials ----------
__global__ __launch_bounds__(NTHR) void finalize(
    const float* __restrict__ partials, float* __restrict__ out)
{
    const int b = blockIdx.x;
    float v = 0.f;
    const int c = threadIdx.x >> 6;       // wave 0,1,2 -> channel; wave 3 idle
    const int k = threadIdx.x & 63;
    if (c < 3) v = partials[c * CBLK + b * 64 + k];
    #pragma unroll
    for (int o = 32; o > 0; o >>= 1) v += __shfl_down(v, o);
    __shared__ float sr[3];
    if (c < 3 && k == 0) sr[c] = v;
    __syncthreads();
    if (threadIdx.x == 0) {
        float ts = sr[0], tc = sr[1], tr = sr[2];
        float tot = ts + tc + tr;
        out[     b] = tot;
        out[ 8 + b] = 0.f;
        out[16 + b] = tot;
        out[24 + b] = 0.f;
        out[32 + b] = ts;
        out[40 + b] = tc;
        out[48 + b] = tr;
        out[56 + b] = 0.f;
    }
}

extern "C" void kernel_launch(void* const* d_in, const int* in_sizes, int n_in,
                              void* d_out, int out_size, void* d_ws, size_t ws_size,
                              hipStream_t stream) {
    const float* pred = (const float*)d_in[0];
    const int*   inst = (const int*)d_in[1];
    // d_in[2] = label (unused by the reference)
    const float* gtR  = (const float*)d_in[3];
    const float* gts  = (const float*)d_in[4];
    const float* gtc  = (const float*)d_in[5];
    const float* gci  = (const float*)d_in[6];
    const int*   ign  = (const int*)d_in[7];
    float* out = (float*)d_out;

    int*    g_counts = (int*)d_ws;
    float*  g_lut    = (float*)((char*)d_ws + 4096);
    float*  partials = (float*)((char*)d_ws + 8192);      // 1536 floats
    uchar4* wbp      = (uchar4*)((char*)d_ws + 65536);    // 4.72 MB
    const size_t need_bytes = 65536 + (size_t)B_IMG * HW;
    const int use_bytes = (ws_size >= need_bytes) ? 1 : 0;

    hipMemsetAsync(g_counts, 0, B_IMG * MAXI * sizeof(int), stream);

    pass1_count<<<NBLK1, NTHR, 0, stream>>>(inst, ign, gci, g_counts, wbp, use_bytes);
    build_lut<<<B_IMG, 64, 0, stream>>>(g_counts, g_lut);
    if (use_bytes)
        pass2_loss<1><<<NBLK2, NTHR, 0, stream>>>(pred, wbp, inst, ign, gci,
                                                  gtR, gts, gtc, g_lut, partials);
    else
        pass2_loss<0><<<NBLK2, NTHR, 0, stream>>>(pred, wbp, inst, ign, gci,
                                                  gtR, gts, gtc, g_lut, partials);
    finalize<<<B_IMG, NTHR, 0, stream>>>(partials, out);
}

// Round 9
// 53.000 us; speedup vs baseline: 1.4093x; 1.4093x over previous
//
#include <hip/hip_runtime.h>

#define HW     (768*768)       // 589824 pixels per plane
#define N4     (HW/4)          // 147456 float4 groups per plane
#define MAXI   33
#define LUTN   (MAXI+1)        // 34 (entry 33 = weight 0)
#define B_IMG  8
#define NTHR   256
#define NBLK   1536            // 6 blocks/CU; NBLK*NTHR*NJ == 8*N4 exactly
#define NJ     3
#define GPB    (NTHR*NJ)       // 768 groups per block
#define BPI    192             // blocks per image (N4/GPB)

// ws: 0 g_counts int[8][33] | 4096 g_lut float[8][34] | 8192 partials float[NBLK*3]
//     65536 widx byte plane (4.72 MB)

// ---------- Pass 1: ballot histogram + ci-fused widx byte plane ----------
__global__ __launch_bounds__(NTHR, 6) void pass1_count(
    const int* __restrict__ inst, const int* __restrict__ ign,
    const float* __restrict__ gci,
    int* __restrict__ g_counts, uchar4* __restrict__ wbp, int write_bytes)
{
    const int bid  = blockIdx.x;
    const int b    = bid / BPI;
    const int lane = threadIdx.x & 63;
    const int wv   = threadIdx.x >> 6;
    const int4*   ip  = (const int4*)inst;
    const int4*   gp  = (const int4*)ign;
    const float4* cip = (const float4*)gci;

    int acc = 0;   // count for bin == lane (lanes 0..32 hold bins)

    #pragma unroll
    for (int j = 0; j < NJ; ++j) {
        const int g = bid * GPB + j * NTHR + threadIdx.x;
        int4   id4 = ip[g];
        int4   g4  = gp[g];
        float4 ci  = cip[g];
        int c0 = (g4.x == 0) ? id4.x : MAXI;
        int c1 = (g4.y == 0) ? id4.y : MAXI;
        int c2 = (g4.z == 0) ? id4.z : MAXI;
        int c3 = (g4.w == 0) ? id4.w : MAXI;
        if (write_bytes) {
            int e0 = (ci.x != 0.f) ? c0 : MAXI;
            int e1 = (ci.y != 0.f) ? c1 : MAXI;
            int e2 = (ci.z != 0.f) ? c2 : MAXI;
            int e3 = (ci.w != 0.f) ? c3 : MAXI;
            wbp[g] = make_uchar4((unsigned char)e0, (unsigned char)e1,
                                 (unsigned char)e2, (unsigned char)e3);
        }
        for (int k = 0; k < MAXI; ++k) {
            int cc = __popcll(__ballot(c0 == k)) + __popcll(__ballot(c1 == k))
                   + __popcll(__ballot(c2 == k)) + __popcll(__ballot(c3 == k));
            acc += (lane == k) ? cc : 0;
        }
    }

    __shared__ int s_cnt[NTHR / 64][MAXI];
    if (lane < MAXI) s_cnt[wv][lane] = acc;
    __syncthreads();
    if (threadIdx.x < MAXI) {
        int t = 0;
        #pragma unroll
        for (int w = 0; w < NTHR / 64; ++w) t += s_cnt[w][threadIdx.x];
        atomicAdd(&g_counts[b * MAXI + threadIdx.x], t);
    }
}

// ---------- LUT build: one wave per image (kernel boundary = coherence) ----------
__global__ __launch_bounds__(64) void build_lut(
    const int* __restrict__ g_counts, float* __restrict__ g_lut)
{
    const int b = blockIdx.x;
    const int k = threadIdx.x;
    int cnt = (k < MAXI) ? g_counts[b * MAXI + k] : 0;
    unsigned long long m = __ballot(k >= 1 && k < MAXI && cnt > 0);
    float n = fmaxf((float)__popcll(m), 1.0f);
    if (k < LUTN) {
        float f = 0.f;
        if (k < MAXI) {
            f = 1.0f / fmaxf((float)cnt, 1.0f);
            if (k > 0) f /= n;
        }
        g_lut[b * LUTN + k] = f;
    }
}

// ---------- Pass 2: weighted L1; ALL lut gathers hoisted before the stream loop ----------
template<int SRC>
__global__ __launch_bounds__(NTHR, 6) void pass2_loss(
    const float* __restrict__ pred, const uchar4* __restrict__ wbp,
    const int* __restrict__ inst, const int* __restrict__ ign,
    const float* __restrict__ gci,
    const float* __restrict__ gtR, const float* __restrict__ gts,
    const float* __restrict__ gtc,
    const float* __restrict__ g_lut, float* __restrict__ partials)
{
    const int bid = blockIdx.x;
    const int b   = bid / BPI;

    __shared__ float lut[LUTN];
    if (threadIdx.x < LUTN) lut[threadIdx.x] = g_lut[b * LUTN + threadIdx.x];
    __syncthreads();

    const float4* p0 = (const float4*)pred + (size_t)(b * 3 + 0) * N4;
    const float4* p1 = (const float4*)pred + (size_t)(b * 3 + 1) * N4;
    const float4* p2 = (const float4*)pred + (size_t)(b * 3 + 2) * N4;
    const float4* Rp = (const float4*)gtR;
    const float4* sp = (const float4*)gts;
    const float4* cp = (const float4*)gtc;
    const int4*   ipp = (const int4*)inst;
    const int4*   gpp = (const int4*)ign;
    const float4* cip = (const float4*)gci;

    const int g0 = bid * GPB + threadIdx.x;
    const int g1 = g0 + NTHR;
    const int g2 = g0 + 2 * NTHR;

    // ---- hoisted gather phase: 12 weight values into named registers ----
    int wA0, wA1, wA2, wA3, wB0, wB1, wB2, wB3, wC0, wC1, wC2, wC3;
    if constexpr (SRC) {
        uchar4 uA = wbp[g0];
        uchar4 uB = wbp[g1];
        uchar4 uC = wbp[g2];
        wA0 = uA.x; wA1 = uA.y; wA2 = uA.z; wA3 = uA.w;
        wB0 = uB.x; wB1 = uB.y; wB2 = uB.z; wB3 = uB.w;
        wC0 = uC.x; wC1 = uC.y; wC2 = uC.z; wC3 = uC.w;
    } else {
        int4 iA = ipp[g0], iB = ipp[g1], iC = ipp[g2];
        int4 gA = gpp[g0], gB = gpp[g1], gC = gpp[g2];
        float4 cA = cip[g0], cB = cip[g1], cC = cip[g2];
        wA0 = (gA.x == 0 && cA.x != 0.f) ? iA.x : MAXI;
        wA1 = (gA.y == 0 && cA.y != 0.f) ? iA.y : MAXI;
        wA2 = (gA.z == 0 && cA.z != 0.f) ? iA.z : MAXI;
        wA3 = (gA.w == 0 && cA.w != 0.f) ? iA.w : MAXI;
        wB0 = (gB.x == 0 && cB.x != 0.f) ? iB.x : MAXI;
        wB1 = (gB.y == 0 && cB.y != 0.f) ? iB.y : MAXI;
        wB2 = (gB.z == 0 && cB.z != 0.f) ? iB.z : MAXI;
        wB3 = (gB.w == 0 && cB.w != 0.f) ? iB.w : MAXI;
        wC0 = (gC.x == 0 && cC.x != 0.f) ? iC.x : MAXI;
        wC1 = (gC.y == 0 && cC.y != 0.f) ? iC.y : MAXI;
        wC2 = (gC.z == 0 && cC.z != 0.f) ? iC.z : MAXI;
        wC3 = (gC.w == 0 && cC.w != 0.f) ? iC.w : MAXI;
    }
    const float fA0 = lut[wA0], fA1 = lut[wA1], fA2 = lut[wA2], fA3 = lut[wA3];
    const float fB0 = lut[wB0], fB1 = lut[wB1], fB2 = lut[wB2], fB3 = lut[wB3];
    const float fC0 = lut[wC0], fC1 = lut[wC1], fC2 = lut[wC2], fC3 = lut[wC3];

    // ---- streaming phase: pure float4 loads + FMA, no LDS on critical path ----
    float as = 0.f, ac = 0.f, ar = 0.f;

#define CONSUME(G, LG, F0, F1, F2, F3) { \
    float4 a  = p0[LG]; \
    float4 bb = p1[LG]; \
    float4 rr = p2[LG]; \
    float4 R  = Rp[G]; \
    float4 si = sp[G]; \
    float4 co = cp[G]; \
    as += F0 * fabsf(a.x - si.x) + F1 * fabsf(a.y - si.y) \
        + F2 * fabsf(a.z - si.z) + F3 * fabsf(a.w - si.w); \
    ac += F0 * fabsf(bb.x - co.x) + F1 * fabsf(bb.y - co.y) \
        + F2 * fabsf(bb.z - co.z) + F3 * fabsf(bb.w - co.w); \
    ar += F0 * fabsf(rr.x - __logf(R.x + 1.f)) + F1 * fabsf(rr.y - __logf(R.y + 1.f)) \
        + F2 * fabsf(rr.z - __logf(R.z + 1.f)) + F3 * fabsf(rr.w - __logf(R.w + 1.f)); }

    CONSUME(g0, g0 - b * N4, fA0, fA1, fA2, fA3)
    CONSUME(g1, g1 - b * N4, fB0, fB1, fB2, fB3)
    CONSUME(g2, g2 - b * N4, fC0, fC1, fC2, fC3)
#undef CONSUME

    #pragma unroll
    for (int o = 32; o > 0; o >>= 1) {
        as += __shfl_down(as, o);
        ac += __shfl_down(ac, o);
        ar += __shfl_down(ar, o);
    }
    __shared__ float sred[3][NTHR / 64];
    const int wv = threadIdx.x >> 6, lane = threadIdx.x & 63;
    if (lane == 0) { sred[0][wv] = as; sred[1][wv] = ac; sred[2][wv] = ar; }
    __syncthreads();
    if (threadIdx.x == 0) {
        float ts = 0.f, tc = 0.f, tr = 0.f;
        #pragma unroll
        for (int w = 0; w < NTHR / 64; ++w) { ts += sred[0][w]; tc += sred[1][w]; tr += sred[2][w]; }
        float* pp = partials + (size_t)bid * 3;
        pp[0] = ts; pp[1] = tc; pp[2] = tr;
    }
}

// ---------- Finalize: deterministic reduce of 192 block-partials per image ----------
__global__ __launch_bounds__(NTHR) void finalize(
    const float* __restrict__ partials, float* __restrict__ out)
{
    const int b = blockIdx.x;
    float s = 0.f, c = 0.f, r = 0.f;
    if (threadIdx.x < BPI) {
        const float* pp = partials + (size_t)(b * BPI + threadIdx.x) * 3;
        s = pp[0]; c = pp[1]; r = pp[2];
    }
    #pragma unroll
    for (int o = 32; o > 0; o >>= 1) {
        s += __shfl_down(s, o);
        c += __shfl_down(c, o);
        r += __shfl_down(r, o);
    }
    __shared__ float sr[3][NTHR / 64];
    const int wv = threadIdx.x >> 6, lane = threadIdx.x & 63;
    if (lane == 0) { sr[0][wv] = s; sr[1][wv] = c; sr[2][wv] = r; }
    __syncthreads();
    if (threadIdx.x == 0) {
        float ts = 0.f, tc = 0.f, tr = 0.f;
        #pragma unroll
        for (int w = 0; w < NTHR / 64; ++w) { ts += sr[0][w]; tc += sr[1][w]; tr += sr[2][w]; }
        float tot = ts + tc + tr;
        out[     b] = tot;
        out[ 8 + b] = 0.f;
        out[16 + b] = tot;
        out[24 + b] = 0.f;
        out[32 + b] = ts;
        out[40 + b] = tc;
        out[48 + b] = tr;
        out[56 + b] = 0.f;
    }
}

extern "C" void kernel_launch(void* const* d_in, const int* in_sizes, int n_in,
                              void* d_out, int out_size, void* d_ws, size_t ws_size,
                              hipStream_t stream) {
    const float* pred = (const float*)d_in[0];
    const int*   inst = (const int*)d_in[1];
    // d_in[2] = label (unused by the reference)
    const float* gtR  = (const float*)d_in[3];
    const float* gts  = (const float*)d_in[4];
    const float* gtc  = (const float*)d_in[5];
    const float* gci  = (const float*)d_in[6];
    const int*   ign  = (const int*)d_in[7];
    float* out = (float*)d_out;

    int*    g_counts = (int*)d_ws;
    float*  g_lut    = (float*)((char*)d_ws + 4096);
    float*  partials = (float*)((char*)d_ws + 8192);      // 1536*3*4 = 18432 B
    uchar4* wbp      = (uchar4*)((char*)d_ws + 65536);    // 4.72 MB
    const size_t need_bytes = 65536 + (size_t)B_IMG * HW;
    const int use_bytes = (ws_size >= need_bytes) ? 1 : 0;

    hipMemsetAsync(g_counts, 0, B_IMG * MAXI * sizeof(int), stream);

    pass1_count<<<NBLK, NTHR, 0, stream>>>(inst, ign, gci, g_counts, wbp, use_bytes);
    build_lut<<<B_IMG, 64, 0, stream>>>(g_counts, g_lut);
    if (use_bytes)
        pass2_loss<1><<<NBLK, NTHR, 0, stream>>>(pred, wbp, inst, ign, gci,
                                                 gtR, gts, gtc, g_lut, partials);
    else
        pass2_loss<0><<<NBLK, NTHR, 0, stream>>>(pred, wbp, inst, ign, gci,
                                                 gtR, gts, gtc, g_lut, partials);
    finalize<<<B_IMG, NTHR, 0, stream>>>(partials, out);
}